// Round 15
// baseline (83.704 us; speedup 1.0000x reference)
//
#include <hip/hip_runtime.h>
#include <math.h>

#define CC 64
#define KK 48
#define HH 4

typedef __attribute__((ext_vector_type(8))) short s16x8;
typedef __attribute__((ext_vector_type(4))) short s16x4;
typedef __attribute__((ext_vector_type(4))) float f32x4;

// ws u16 layout: [0,4096) wq_bf | [4096,8192) wk2T_bf | [8192,12288) wv_bf
//   [12288,16384) opw_bf | [16384,32768) l1_bf | [32768,49152) l2_bf | [49152,53248) ow_bf
// ws f32: [26624,26752) nrm s,t | [26752,26880) bn2 s,t | [26880] flag(int)
// qw: u16 off 57344 [M][4][64] | vfb: u16 after qw [NV][64] | vc4: float4[NV] after vfb
#define QW_OFF_U16 57344
#define CASTB 1536

#define WAVEFENCE() asm volatile("s_waitcnt lgkmcnt(0)" ::: "memory")

__device__ __forceinline__ unsigned short f2bf(float f) {
  return (unsigned short)((__float_as_uint(f) + 0x8000u) >> 16);  // round-half-up
}
__device__ __forceinline__ float bf2f(unsigned short h) {
  return __uint_as_float(((unsigned)h) << 16);
}
// pack two f32 -> 2x bf16 (RNE) in one VALU op
__device__ __forceinline__ unsigned cvtpk(float lo, float hi) {
  unsigned r;
  asm("v_cvt_pk_bf16_f32 %0, %1, %2" : "=v"(r) : "v"(lo), "v"(hi));
  return r;
}

// ---------------- fused setup: prep [0,210) | castv [210,210+CASTB) | qprep rest ----------------
__global__ __launch_bounds__(256) void setup_kernel(
    const float* __restrict__ ipw, const float* __restrict__ opw,
    const float* __restrict__ l1w, const float* __restrict__ l2w,
    const float* __restrict__ ow,
    const float* __restrict__ ng, const float* __restrict__ nb,
    const float* __restrict__ nm, const float* __restrict__ nv,
    const float* __restrict__ b2g, const float* __restrict__ b2b,
    const float* __restrict__ b2m, const float* __restrict__ b2v,
    const unsigned char* __restrict__ km,
    const float* __restrict__ vf, const float* __restrict__ vcoord,
    const float* __restrict__ qcoord, const float* __restrict__ qpw,
    const float* __restrict__ qpb, const float* __restrict__ ipb,
    float* __restrict__ ws,
    unsigned short* __restrict__ vfb, float4* __restrict__ vc4,
    unsigned short* __restrict__ qw_out, int M, int NV)
{
  unsigned short* wsu = (unsigned short*)ws;
  const int b = blockIdx.x;

  if (b < 210) {                       // ---- prep part ----
    if (b == 209) {                    // mask dtype detect
      int any = 0;
      for (int i = threadIdx.x; i < 4096; i += 256)
        if ((i & 3) && km[i]) any = 1;
      __shared__ int sb;
      if (threadIdx.x == 0) sb = 0;
      __syncthreads();
      if (any) atomicOr(&sb, 1);
      __syncthreads();
      if (threadIdx.x == 0) ((int*)ws)[26880] = sb;
      return;
    }
    int e = b * 256 + threadIdx.x;
    if (e < 4096)        wsu[e] = f2bf(ipw[e]);
    else if (e < 8192)  { int i = e - 4096; int h = i >> 10, c = (i >> 4) & 63, d = i & 15;
                          wsu[e] = f2bf(ipw[(size_t)(64 + h * 16 + d) * 64 + c]); }
    else if (e < 12288)  wsu[e] = f2bf(ipw[e]);
    else if (e < 16384)  wsu[e] = f2bf(opw[e - 12288]);
    else if (e < 32768)  wsu[e] = f2bf(l1w[e - 16384]);
    else if (e < 49152)  wsu[e] = f2bf(l2w[e - 32768]);
    else if (e < 53248)  wsu[e] = f2bf(ow[e - 49152]);
    else if (e < 53312) { int c = e - 53248; float s = ng[c] / sqrtf(nv[c] + 1e-5f);
                          ws[26624 + c] = s; ws[26624 + 64 + c] = nb[c] - nm[c] * s; }
    else if (e < 53376) { int c = e - 53312; float s = b2g[c] / sqrtf(b2v[c] + 1e-5f);
                          ws[26752 + c] = s; ws[26752 + 64 + c] = b2b[c] - b2m[c] * s; }
    return;
  }

  if (b < 210 + CASTB) {               // ---- castv part (grid-stride) ----
    const int i0 = (b - 210) * 256 + threadIdx.x;
    const int stride = CASTB * 256;
    for (int i = i0; i < NV * 16; i += stride) {
      const float4 v = *(const float4*)(vf + (size_t)i * 4);
      s16x4 p; p[0] = (short)f2bf(v.x); p[1] = (short)f2bf(v.y);
      p[2] = (short)f2bf(v.z); p[3] = (short)f2bf(v.w);
      *(s16x4*)(vfb + (size_t)i * 4) = p;
    }
    for (int i = i0; i < NV; i += stride)
      vc4[i] = make_float4(vcoord[i * 3], vcoord[i * 3 + 1], vcoord[i * 3 + 2], 0.f);
    return;
  }

  // ---- qprep part: stage wq/wk to LDS coalesced, then MFMA ----
  {
    __shared__ __align__(16) unsigned short wql[4096];   // wq row-major, swz
    __shared__ __align__(16) unsigned short wkTl[4096];  // wk transposed [c][r], swz
    __shared__ __align__(16) unsigned short xa[4][1024];
    __shared__ float qc[4][48];
    const int w = threadIdx.x >> 6, l = threadIdx.x & 63;
    const int col = l & 15, lg = l >> 4;
    const int r0 = (b - 210 - CASTB) * 64 + w * 16;

    for (int i = threadIdx.x; i < 4096; i += 256) {
      const int r = i >> 6, d = i & 63;
      wql[i ^ ((r & 7) << 3)] = f2bf(ipw[i]);                       // wq[r][d]
      wkTl[(d * 64 + r) ^ ((d & 7) << 3)] = f2bf(ipw[4096 + i]);    // wk[r][d] -> [d][r]
    }
    if (l < 48) {
      int gi = r0 * 3 + l;
      qc[w][l] = (gi < M * 3) ? qcoord[gi] : 0.f;
    }
    const int c0 = col * 4;
    const float4 wA = *(const float4*)(qpw + c0 * 3);
    const float4 wB = *(const float4*)(qpw + c0 * 3 + 4);
    const float4 wC = *(const float4*)(qpw + c0 * 3 + 8);
    const float4 bq4 = *(const float4*)(qpb + c0);
    __syncthreads();

    #pragma unroll
    for (int i = 0; i < 4; ++i) {
      const int row = i * 4 + lg;
      const float x = qc[w][row * 3 + 0], y = qc[w][row * 3 + 1], z = qc[w][row * 3 + 2];
      s16x4 p;
      p[0] = (short)f2bf(fmaxf(wA.x * x + wA.y * y + wA.z * z + bq4.x, 0.f));
      p[1] = (short)f2bf(fmaxf(wA.w * x + wB.x * y + wB.y * z + bq4.y, 0.f));
      p[2] = (short)f2bf(fmaxf(wB.z * x + wB.w * y + wC.x * z + bq4.z, 0.f));
      p[3] = (short)f2bf(fmaxf(wC.y * x + wC.z * y + wC.w * z + bq4.w, 0.f));
      *(s16x4*)&xa[w][(row * 64 + c0) ^ ((row & 7) << 3)] = p;
    }
    __syncthreads();

    {
      s16x8 af0 = *(const s16x8*)&xa[w][(col * 64 + 0 + lg * 8) ^ ((col & 7) << 3)];
      s16x8 af1 = *(const s16x8*)&xa[w][(col * 64 + 32 + lg * 8) ^ ((col & 7) << 3)];
      f32x4 qv[4];
      #pragma unroll
      for (int nt = 0; nt < 4; ++nt) {
        const int n = nt * 16 + col;
        f32x4 acc = {0.f, 0.f, 0.f, 0.f};
        acc = __builtin_amdgcn_mfma_f32_16x16x32_bf16(af0,
                *(const s16x8*)&wql[(n * 64 + 0 + lg * 8) ^ ((col & 7) << 3)], acc, 0, 0, 0);
        acc = __builtin_amdgcn_mfma_f32_16x16x32_bf16(af1,
                *(const s16x8*)&wql[(n * 64 + 32 + lg * 8) ^ ((col & 7) << 3)], acc, 0, 0, 0);
        qv[nt] = acc;
      }
      __syncthreads();
      #pragma unroll
      for (int nt = 0; nt < 4; ++nt) {
        const int n = nt * 16 + col;
        const float bb = ipb[n];
        #pragma unroll
        for (int r = 0; r < 4; ++r) {
          const int row = lg * 4 + r;
          xa[w][(row * 64 + n) ^ ((row & 7) << 3)] = f2bf((qv[nt][r] + bb) * 0.25f);
        }
      }
    }
    __syncthreads();

    #pragma unroll
    for (int h = 0; h < HH; ++h) {
      s16x8 a = {0, 0, 0, 0, 0, 0, 0, 0};
      if (lg < 2)
        a = *(const s16x8*)&xa[w][(col * 64 + h * 16 + lg * 8) ^ ((col & 7) << 3)];
      #pragma unroll
      for (int nt = 0; nt < 4; ++nt) {
        const int n = nt * 16 + col;
        s16x8 bf = {0, 0, 0, 0, 0, 0, 0, 0};
        if (lg < 2)
          bf = *(const s16x8*)&wkTl[(n * 64 + h * 16 + lg * 8) ^ ((col & 7) << 3)];
        f32x4 acc = {0.f, 0.f, 0.f, 0.f};
        acc = __builtin_amdgcn_mfma_f32_16x16x32_bf16(a, bf, acc, 0, 0, 0);
        #pragma unroll
        for (int r = 0; r < 4; ++r) {
          const int m = lg * 4 + r;
          if (r0 + m < M)
            qw_out[(size_t)(r0 + m) * 256 + h * 64 + n] = f2bf(acc[r]);
        }
      }
    }
  }
}

// ---------------- attn_hot: r14-proven + cvt_pk bf16 pack in P5 ----------------
__global__ __launch_bounds__(256, 4) void attn_hot(
    const unsigned short* __restrict__ vfb, const float4* __restrict__ vc4,
    const float* __restrict__ qcoord, const int* __restrict__ kidx,
    const unsigned char* __restrict__ km8, const int* __restrict__ km32,
    const int* __restrict__ maskfmt,
    const float* __restrict__ kpw, const float* __restrict__ kpb,
    const float* __restrict__ ipb,
    const unsigned short* __restrict__ wv_bf,
    const unsigned short* __restrict__ qw_pre,
    float* __restrict__ out, int M)
{
  __shared__ __align__(16) unsigned short shq[4][3456];
  __shared__ __align__(16) unsigned short wvl[4096];
  const int w = threadIdx.x >> 6, l = threadIdx.x & 63;
  const int col = l & 15, lg = l >> 4;
  int m = blockIdx.x * 4 + w;
  if (m >= M) m = M - 1;
  unsigned short* sh = shq[w];
  float* relf = (float*)(sh + 3072);
  const int is_u8 = *maskfmt;

  #pragma unroll
  for (int i = 0; i < 2; ++i) {
    const int ch = threadIdx.x * 2 + i;
    const int n = ch >> 3, g = ch & 7;
    const s16x8 v = *(const s16x8*)(wv_bf + n * 64 + g * 8);
    *(s16x8*)&wvl[n * 64 + ((g ^ (n & 7)) << 3)] = v;
  }

  const float qx = qcoord[m * 3 + 0], qy = qcoord[m * 3 + 1], qz = qcoord[m * 3 + 2];
  const int c0 = col * 4;
  const float4 kwA = *(const float4*)(kpw + c0 * 3);
  const float4 kwB = *(const float4*)(kpw + c0 * 3 + 4);
  const float4 kwC = *(const float4*)(kpw + c0 * 3 + 8);
  const float4 kbv = *(const float4*)(kpb + c0);

  // qw B-frags issued early: latency hides under P1/P5
  const s16x8 qb0 = *(const s16x8*)(qw_pre + (size_t)m * 256 + (col & 3) * 64 + 0 + lg * 8);
  const s16x8 qb1 = *(const s16x8*)(qw_pre + (size_t)m * 256 + (col & 3) * 64 + 32 + lg * 8);

  unsigned char msk = 0;
  if (l < KK) {
    const int idx = kidx[m * KK + l];
    msk = is_u8 ? km8[m * KK + l] : (unsigned char)(km32[m * KK + l] != 0);
    const float4 vc = vc4[idx];
    float4 rr;
    rr.x = vc.x - qx; rr.y = vc.y - qy; rr.z = vc.z - qz;
    rr.w = __int_as_float(idx);
    *(float4*)(relf + l * 4) = rr;
  }
  const unsigned long long bm = __ballot(l < KK && msk);
  __syncthreads();                       // covers wvl (cross-wave) + relf

  #pragma unroll
  for (int half = 0; half < 2; ++half) {
    float4 ra[6]; s16x4 va[6];
    #pragma unroll
    for (int j = 0; j < 6; ++j) {
      const int k = half * 24 + j * 4 + lg;
      ra[j] = *(const float4*)(relf + k * 4);
      va[j] = *(const s16x4*)(vfb + (size_t)__float_as_int(ra[j].w) * 64 + c0);
    }
    #pragma unroll
    for (int j = 0; j < 6; ++j) {
      const int k = half * 24 + j * 4 + lg;
      const float v0 = bf2f((unsigned short)va[j][0])
                     + fmaxf(kwA.x * ra[j].x + kwA.y * ra[j].y + kwA.z * ra[j].z + kbv.x, 0.f);
      const float v1 = bf2f((unsigned short)va[j][1])
                     + fmaxf(kwA.w * ra[j].x + kwB.x * ra[j].y + kwB.y * ra[j].z + kbv.y, 0.f);
      const float v2 = bf2f((unsigned short)va[j][2])
                     + fmaxf(kwB.z * ra[j].x + kwB.w * ra[j].y + kwC.x * ra[j].z + kbv.z, 0.f);
      const float v3 = bf2f((unsigned short)va[j][3])
                     + fmaxf(kwC.y * ra[j].x + kwC.z * ra[j].y + kwC.w * ra[j].z + kbv.w, 0.f);
      uint2 pp;
      pp.x = cvtpk(v0, v1);              // 1 VALU op replaces 2x f2bf + pack
      pp.y = cvtpk(v2, v3);
      *(uint2*)&sh[(k * 64 + c0) ^ ((k & 7) << 3)] = pp;
    }
  }
  WAVEFENCE();

  // ---- scores via MFMA ----
  s16x8 af[3][2];
  #pragma unroll
  for (int mt = 0; mt < 3; ++mt)
    #pragma unroll
    for (int kst = 0; kst < 2; ++kst) {
      const int row = mt * 16 + col;
      af[mt][kst] = *(const s16x8*)&sh[(row * 64 + kst * 32 + lg * 8) ^ ((row & 7) << 3)];
    }
  f32x4 sc[3];
  sc[0] = sc[1] = sc[2] = (f32x4){0.f, 0.f, 0.f, 0.f};
  __builtin_amdgcn_s_setprio(1);
  #pragma unroll
  for (int mt = 0; mt < 3; ++mt) {
    sc[mt] = __builtin_amdgcn_mfma_f32_16x16x32_bf16(af[mt][0], qb0, sc[mt], 0, 0, 0);
    sc[mt] = __builtin_amdgcn_mfma_f32_16x16x32_bf16(af[mt][1], qb1, sc[mt], 0, 0, 0);
  }
  __builtin_amdgcn_s_setprio(0);

  // ---- softmax ----
  float sv[12];
  {
    float mx = -INFINITY;
    #pragma unroll
    for (int mt = 0; mt < 3; ++mt)
      #pragma unroll
      for (int r = 0; r < 4; ++r) {
        const int key = mt * 16 + lg * 4 + r;
        float v = sc[mt][r];
        if ((bm >> key) & 1ull) v = -1e30f;
        sv[mt * 4 + r] = v;
        mx = fmaxf(mx, v);
      }
    mx = fmaxf(mx, __shfl_xor(mx, 16, 64));
    mx = fmaxf(mx, __shfl_xor(mx, 32, 64));
    float sum = 0.f;
    #pragma unroll
    for (int i = 0; i < 12; ++i) { float e = __expf(sv[i] - mx); sv[i] = e; sum += e; }
    sum += __shfl_xor(sum, 16, 64);
    sum += __shfl_xor(sum, 32, 64);
    const float inv = 1.f / sum;
    #pragma unroll
    for (int i = 0; i < 12; ++i) sv[i] *= inv;
  }
  if (col < HH) {
    #pragma unroll
    for (int mt = 0; mt < 3; ++mt)
      #pragma unroll
      for (int r = 0; r < 4; ++r)
        relf[(mt * 16 + lg * 4 + r) * 4 + col] = sv[mt * 4 + r];
  }
  WAVEFENCE();

  // ---- vv = kin @ wv^T, then o[c] = sum_k a[k][h(c)]*vv[k][c] + bv ----
  f32x4 vva[4][3];
  __builtin_amdgcn_s_setprio(1);
  #pragma unroll
  for (int nt = 0; nt < 4; ++nt) {
    const int n = nt * 16 + col;
    vva[nt][0] = vva[nt][1] = vva[nt][2] = (f32x4){0.f, 0.f, 0.f, 0.f};
    #pragma unroll
    for (int kst = 0; kst < 2; ++kst) {
      const s16x8 bb = *(const s16x8*)&wvl[(n * 64 + kst * 32 + lg * 8) ^ ((n & 7) << 3)];
      vva[nt][0] = __builtin_amdgcn_mfma_f32_16x16x32_bf16(af[0][kst], bb, vva[nt][0], 0, 0, 0);
      vva[nt][1] = __builtin_amdgcn_mfma_f32_16x16x32_bf16(af[1][kst], bb, vva[nt][1], 0, 0, 0);
      vva[nt][2] = __builtin_amdgcn_mfma_f32_16x16x32_bf16(af[2][kst], bb, vva[nt][2], 0, 0, 0);
    }
  }
  __builtin_amdgcn_s_setprio(0);
  float op[4] = {0.f, 0.f, 0.f, 0.f};
  #pragma unroll
  for (int mt = 0; mt < 3; ++mt)
    #pragma unroll
    for (int r = 0; r < 4; ++r) {
      const float4 a4 = *(const float4*)(relf + (mt * 16 + lg * 4 + r) * 4);
      op[0] += a4.x * vva[0][mt][r];
      op[1] += a4.y * vva[1][mt][r];
      op[2] += a4.z * vva[2][mt][r];
      op[3] += a4.w * vva[3][mt][r];
    }
  #pragma unroll
  for (int nt = 0; nt < 4; ++nt) {
    op[nt] += __shfl_xor(op[nt], 16, 64);
    op[nt] += __shfl_xor(op[nt], 32, 64);
  }
  {
    float oo = (lg == 0) ? op[0] : (lg == 1) ? op[1] : (lg == 2) ? op[2] : op[3];
    oo += ipb[2 * CC + lg * 16 + col];
    out[(size_t)m * CC + lg * 16 + col] = oo;
  }
}

// ---------------- chain2: 16 rows/block, 4 cooperative waves ----------------
__global__ __launch_bounds__(256, 4) void chain2_kernel(
    float* __restrict__ inout, const unsigned short* __restrict__ wsu,
    const float* __restrict__ opb, const float* __restrict__ l1b,
    const float* __restrict__ l2b, const float* __restrict__ ob,
    const float* __restrict__ nrm, const float* __restrict__ bn2, int M)
{
  __shared__ __align__(16) unsigned short XA[1024];
  __shared__ __align__(16) unsigned short XH[4096];
  __shared__ __align__(16) unsigned short XB[1024];
  const int w = threadIdx.x >> 6, l = threadIdx.x & 63;
  const int col = l & 15, lg = l >> 4;
  const int r0 = blockIdx.x * 16;

  const unsigned short* opw_bf = wsu + 12288;
  const unsigned short* l1_bf  = wsu + 16384;
  const unsigned short* l2_bf  = wsu + 32768;
  const unsigned short* ow_bf  = wsu + 49152;

  {
    const int i = threadIdx.x;
    const int row = i >> 4, cb = (i & 15) * 4;
    float4 v = make_float4(0.f, 0.f, 0.f, 0.f);
    if (r0 + row < M) v = *(const float4*)(&inout[(size_t)(r0 + row) * 64 + cb]);
    s16x4 p; p[0] = (short)f2bf(v.x); p[1] = (short)f2bf(v.y);
    p[2] = (short)f2bf(v.z); p[3] = (short)f2bf(v.w);
    *(s16x4*)&XA[(row * 64 + cb) ^ ((row & 7) << 3)] = p;
  }
  __syncthreads();

  s16x8 afa[2];
  #pragma unroll
  for (int kst = 0; kst < 2; ++kst)
    afa[kst] = *(const s16x8*)&XA[(col * 64 + kst * 32 + lg * 8) ^ ((col & 7) << 3)];
  f32x4 att;
  {
    f32x4 acc = {0.f, 0.f, 0.f, 0.f};
    #pragma unroll
    for (int kst = 0; kst < 2; ++kst) {
      const s16x8 bb = *(const s16x8*)&opw_bf[(w * 16 + col) * 64 + kst * 32 + lg * 8];
      acc = __builtin_amdgcn_mfma_f32_16x16x32_bf16(afa[kst], bb, acc, 0, 0, 0);
    }
    const float bias = opb[w * 16 + col];
    #pragma unroll
    for (int r = 0; r < 4; ++r) {
      acc[r] += bias;
      const int row = lg * 4 + r;
      XB[(row * 64 + w * 16 + col) ^ ((row & 7) << 3)] = (short)f2bf(acc[r]);
    }
    att = acc;
  }
  __syncthreads();

  {
    s16x8 afb[2];
    #pragma unroll
    for (int kst = 0; kst < 2; ++kst)
      afb[kst] = *(const s16x8*)&XB[(col * 64 + kst * 32 + lg * 8) ^ ((col & 7) << 3)];
    #pragma unroll
    for (int nt2 = 0; nt2 < 4; ++nt2) {
      const int ntg = w * 4 + nt2;
      f32x4 acc = {0.f, 0.f, 0.f, 0.f};
      #pragma unroll
      for (int kst = 0; kst < 2; ++kst) {
        const s16x8 bb = *(const s16x8*)&l1_bf[(ntg * 16 + col) * 64 + kst * 32 + lg * 8];
        acc = __builtin_amdgcn_mfma_f32_16x16x32_bf16(afb[kst], bb, acc, 0, 0, 0);
      }
      const float bias = l1b[ntg * 16 + col];
      #pragma unroll
      for (int r = 0; r < 4; ++r) {
        const float h = fmaxf(acc[r] + bias, 0.f);
        const int row = lg * 4 + r;
        XH[(row * 256 + ntg * 16 + col) ^ ((row & 7) << 3)] = (short)f2bf(h);
      }
    }
  }
  __syncthreads();

  {
    s16x8 afh[8];
    #pragma unroll
    for (int kst = 0; kst < 8; ++kst)
      afh[kst] = *(const s16x8*)&XH[(col * 256 + kst * 32 + lg * 8) ^ ((col & 7) << 3)];
    f32x4 acc = {0.f, 0.f, 0.f, 0.f};
    #pragma unroll
    for (int kst = 0; kst < 8; ++kst) {
      const s16x8 bb = *(const s16x8*)&l2_bf[(w * 16 + col) * 256 + kst * 32 + lg * 8];
      acc = __builtin_amdgcn_mfma_f32_16x16x32_bf16(afh[kst], bb, acc, 0, 0, 0);
    }
    const int nc = w * 16 + col;
    const float bias = l2b[nc], sN = nrm[nc], tN = nrm[64 + nc];
    __syncthreads();                     // G2's XB reads done before overwrite
    #pragma unroll
    for (int r = 0; r < 4; ++r) {
      const float x = (att[r] + acc[r] + bias) * sN + tN;
      const int row = lg * 4 + r;
      XB[(row * 64 + nc) ^ ((row & 7) << 3)] = (short)f2bf(x);
    }
  }
  __syncthreads();

  {
    s16x8 afx[2];
    #pragma unroll
    for (int kst = 0; kst < 2; ++kst)
      afx[kst] = *(const s16x8*)&XB[(col * 64 + kst * 32 + lg * 8) ^ ((col & 7) << 3)];
    f32x4 acc = {0.f, 0.f, 0.f, 0.f};
    #pragma unroll
    for (int kst = 0; kst < 2; ++kst) {
      const s16x8 bb = *(const s16x8*)&ow_bf[(w * 16 + col) * 64 + kst * 32 + lg * 8];
      acc = __builtin_amdgcn_mfma_f32_16x16x32_bf16(afx[kst], bb, acc, 0, 0, 0);
    }
    const int nc = w * 16 + col;
    const float bias = ob[nc], sB = bn2[nc], tB = bn2[64 + nc];
    #pragma unroll
    for (int r = 0; r < 4; ++r) {
      const float y = fmaxf((acc[r] + bias) * sB + tB, 0.f);
      const int q = r0 + lg * 4 + r;
      if (q < M) inout[(size_t)q * 64 + nc] = y;
    }
  }
}

// ---------------- fallback kernels (ws too small): r11-proven ----------------
__global__ __launch_bounds__(256) void prep_kernel(
    const float* __restrict__ ipw, const float* __restrict__ opw,
    const float* __restrict__ l1w, const float* __restrict__ l2w,
    const float* __restrict__ ow,
    const float* __restrict__ ng, const float* __restrict__ nb,
    const float* __restrict__ nm, const float* __restrict__ nv,
    const float* __restrict__ b2g, const float* __restrict__ b2b,
    const float* __restrict__ b2m, const float* __restrict__ b2v,
    const unsigned char* __restrict__ km,
    float* __restrict__ ws)
{
  unsigned short* wsu = (unsigned short*)ws;
  if (blockIdx.x == 209) {
    int any = 0;
    for (int i = threadIdx.x; i < 4096; i += 256)
      if ((i & 3) && km[i]) any = 1;
    __shared__ int sb;
    if (threadIdx.x == 0) sb = 0;
    __syncthreads();
    if (any) atomicOr(&sb, 1);
    __syncthreads();
    if (threadIdx.x == 0) ((int*)ws)[26880] = sb;
    return;
  }
  int e = blockIdx.x * 256 + threadIdx.x;
  if (e < 4096)        wsu[e] = f2bf(ipw[e]);
  else if (e < 8192)  { int i = e - 4096; int h = i >> 10, c = (i >> 4) & 63, d = i & 15;
                        wsu[e] = f2bf(ipw[(size_t)(64 + h * 16 + d) * 64 + c]); }
  else if (e < 12288)  wsu[e] = f2bf(ipw[e]);
  else if (e < 16384)  wsu[e] = f2bf(opw[e - 12288]);
  else if (e < 32768)  wsu[e] = f2bf(l1w[e - 16384]);
  else if (e < 49152)  wsu[e] = f2bf(l2w[e - 32768]);
  else if (e < 53248)  wsu[e] = f2bf(ow[e - 49152]);
  else if (e < 53312) { int c = e - 53248; float s = ng[c] / sqrtf(nv[c] + 1e-5f);
                        ws[26624 + c] = s; ws[26624 + 64 + c] = nb[c] - nm[c] * s; }
  else if (e < 53376) { int c = e - 53312; float s = b2g[c] / sqrtf(b2v[c] + 1e-5f);
                        ws[26752 + c] = s; ws[26752 + 64 + c] = b2b[c] - b2m[c] * s; }
}

__global__ __launch_bounds__(256, 4) void attn_fallback(
    const float* __restrict__ vfeat, const float* __restrict__ vcoord,
    const float* __restrict__ qcoord, const int* __restrict__ kidx,
    const unsigned char* __restrict__ km8, const int* __restrict__ km32,
    const int* __restrict__ maskfmt,
    const float* __restrict__ qpw, const float* __restrict__ qpb,
    const float* __restrict__ kpw, const float* __restrict__ kpb,
    const float* __restrict__ ipb,
    const unsigned short* __restrict__ wq_bf,
    const unsigned short* __restrict__ wk2T_bf,
    const unsigned short* __restrict__ wv_bf,
    float* __restrict__ out, int M)
{
  __shared__ __align__(16) unsigned short shq[4][3776];
  __shared__ __align__(16) unsigned short wvl[4096];
  const int w = threadIdx.x >> 6, l = threadIdx.x & 63;
  const int col = l & 15, lg = l >> 4;
  int m = blockIdx.x * 4 + w;
  if (m >= M) m = M - 1;
  unsigned short* sh = shq[w];
  const int is_u8 = *maskfmt;
  float* relf = (float*)sh + 1696;

  #pragma unroll
  for (int i = 0; i < 2; ++i) {
    const int ch = threadIdx.x * 2 + i;
    const int n = ch >> 3, g = ch & 7;
    const s16x8 v = *(const s16x8*)(wv_bf + n * 64 + g * 8);
    *(s16x8*)&wvl[n * 64 + ((g ^ (n & 7)) << 3)] = v;
  }

  const float qx = qcoord[m * 3 + 0], qy = qcoord[m * 3 + 1], qz = qcoord[m * 3 + 2];
  const int c0 = col * 4;
  const float4 kwA = *(const float4*)(kpw + c0 * 3);
  const float4 kwB = *(const float4*)(kpw + c0 * 3 + 4);
  const float4 kwC = *(const float4*)(kpw + c0 * 3 + 8);
  const float4 kbv = *(const float4*)(kpb + c0);

  {
    float v = qpw[l * 3 + 0] * qx + qpw[l * 3 + 1] * qy + qpw[l * 3 + 2] * qz + qpb[l];
    sh[3328 + l] = f2bf(fmaxf(v, 0.f));
  }
  unsigned char msk = 0;
  if (l < KK) {
    int idx = kidx[m * KK + l];
    msk = is_u8 ? km8[m * KK + l] : (unsigned char)(km32[m * KK + l] != 0);
    relf[l * 4 + 0] = vcoord[idx * 3 + 0] - qx;
    relf[l * 4 + 1] = vcoord[idx * 3 + 1] - qy;
    relf[l * 4 + 2] = vcoord[idx * 3 + 2] - qz;
    relf[l * 4 + 3] = __int_as_float(idx);
  }
  const unsigned long long bm = __ballot(l < KK && msk);
  __syncthreads();

  {
    f32x4 qacc[4];
    #pragma unroll
    for (int nt = 0; nt < 4; ++nt) qacc[nt] = (f32x4){0.f, 0.f, 0.f, 0.f};
    #pragma unroll
    for (int kst = 0; kst < 2; ++kst) {
      const s16x8 a = *(const s16x8*)&sh[3328 + kst * 32 + lg * 8];
      #pragma unroll
      for (int nt = 0; nt < 4; ++nt) {
        const s16x8 b = *(const s16x8*)(wq_bf + (nt * 16 + col) * 64 + kst * 32 + lg * 8);
        qacc[nt] = __builtin_amdgcn_mfma_f32_16x16x32_bf16(a, b, qacc[nt], 0, 0, 0);
      }
    }
    __syncthreads();
    if (lg == 0) {
      #pragma unroll
      for (int nt = 0; nt < 4; ++nt)
        sh[3328 + nt * 16 + col] = f2bf((qacc[nt][0] + ipb[nt * 16 + col]) * 0.25f);
    }
    __syncthreads();
    f32x4 wacc[4];
    #pragma unroll
    for (int nt = 0; nt < 4; ++nt) wacc[nt] = (f32x4){0.f, 0.f, 0.f, 0.f};
    #pragma unroll
    for (int kst = 0; kst < 2; ++kst) {
      const int hblk = kst * 2 + (lg >> 1);
      s16x8 a = {0, 0, 0, 0, 0, 0, 0, 0};
      if (col == hblk) a = *(const s16x8*)&sh[3328 + kst * 32 + lg * 8];
      #pragma unroll
      for (int nt = 0; nt < 4; ++nt) {
        const s16x8 b = *(const s16x8*)(wk2T_bf + hblk * 1024 + (nt * 16 + col) * 16 + (lg & 1) * 8);
        wacc[nt] = __builtin_amdgcn_mfma_f32_16x16x32_bf16(a, b, wacc[nt], 0, 0, 0);
      }
    }
    if (lg == 0) {
      #pragma unroll
      for (int nt = 0; nt < 4; ++nt)
        #pragma unroll
        for (int r = 0; r < 4; ++r)
          sh[3072 + r * 64 + nt * 16 + col] = f2bf(wacc[nt][r]);
    }
  }

  #pragma unroll
  for (int half = 0; half < 2; ++half) {
    float4 ra[6], va[6];
    #pragma unroll
    for (int j = 0; j < 6; ++j) {
      const int k = half * 24 + j * 4 + lg;
      ra[j] = *(const float4*)(relf + k * 4);
      va[j] = *(const float4*)(vfeat + (size_t)__float_as_int(ra[j].w) * 64 + c0);
    }
    #pragma unroll
    for (int j = 0; j < 6; ++j) {
      const int k = half * 24 + j * 4 + lg;
      const float p0 = fmaxf(kwA.x * ra[j].x + kwA.y * ra[j].y + kwA.z * ra[j].z + kbv.x, 0.f);
      const float p1 = fmaxf(kwA.w * ra[j].x + kwB.x * ra[j].y + kwB.y * ra[j].z + kbv.y, 0.f);
      const float p2 = fmaxf(kwB.z * ra[j].x + kwB.w * ra[j].y + kwC.x * ra[j].z + kbv.z, 0.f);
      const float p3 = fmaxf(kwC.y * ra[j].x + kwC.z * ra[j].y + kwC.w * ra[j].z + kbv.w, 0.f);
      s16x4 p;
      p[0] = (short)f2bf(va[j].x + p0); p[1] = (short)f2bf(va[j].y + p1);
      p[2] = (short)f2bf(va[j].z + p2); p[3] = (short)f2bf(va[j].w + p3);
      *(s16x4*)&sh[(k * 64 + c0) ^ ((k & 7) << 3)] = p;
    }
  }
  __syncthreads();

  s16x8 af[3][2];
  #pragma unroll
  for (int mt = 0; mt < 3; ++mt)
    #pragma unroll
    for (int kst = 0; kst < 2; ++kst) {
      const int row = mt * 16 + col;
      af[mt][kst] = *(const s16x8*)&sh[(row * 64 + kst * 32 + lg * 8) ^ ((row & 7) << 3)];
    }
  f32x4 sc[3];
  sc[0] = sc[1] = sc[2] = (f32x4){0.f, 0.f, 0.f, 0.f};
  #pragma unroll
  for (int kst = 0; kst < 2; ++kst) {
    const s16x8 b = *(const s16x8*)&sh[3072 + (col & 3) * 64 + kst * 32 + lg * 8];
    #pragma unroll
    for (int mt = 0; mt < 3; ++mt)
      sc[mt] = __builtin_amdgcn_mfma_f32_16x16x32_bf16(af[mt][kst], b, sc[mt], 0, 0, 0);
  }

  float sv[12];
  {
    float mx = -INFINITY;
    #pragma unroll
    for (int mt = 0; mt < 3; ++mt)
      #pragma unroll
      for (int r = 0; r < 4; ++r) {
        const int key = mt * 16 + lg * 4 + r;
        float v = sc[mt][r];
        if ((bm >> key) & 1ull) v = -1e30f;
        sv[mt * 4 + r] = v;
        mx = fmaxf(mx, v);
      }
    mx = fmaxf(mx, __shfl_xor(mx, 16, 64));
    mx = fmaxf(mx, __shfl_xor(mx, 32, 64));
    float sum = 0.f;
    #pragma unroll
    for (int i = 0; i < 12; ++i) { float e = __expf(sv[i] - mx); sv[i] = e; sum += e; }
    sum += __shfl_xor(sum, 16, 64);
    sum += __shfl_xor(sum, 32, 64);
    const float inv = 1.f / sum;
    #pragma unroll
    for (int i = 0; i < 12; ++i) sv[i] *= inv;
  }

  float op[4];
  #pragma unroll
  for (int nt = 0; nt < 4; ++nt) {
    const int n = nt * 16 + col;
    f32x4 vv0 = {0.f, 0.f, 0.f, 0.f}, vv1 = vv0, vv2 = vv0;
    #pragma unroll
    for (int kst = 0; kst < 2; ++kst) {
      const s16x8 b = *(const s16x8*)&wvl[(n * 64 + kst * 32 + lg * 8) ^ ((n & 7) << 3)];
      vv0 = __builtin_amdgcn_mfma_f32_16x16x32_bf16(af[0][kst], b, vv0, 0, 0, 0);
      vv1 = __builtin_amdgcn_mfma_f32_16x16x32_bf16(af[1][kst], b, vv1, 0, 0, 0);
      vv2 = __builtin_amdgcn_mfma_f32_16x16x32_bf16(af[2][kst], b, vv2, 0, 0, 0);
    }
    const int src = lg * 16 + nt;
    float o = 0.f;
    #pragma unroll
    for (int mt = 0; mt < 3; ++mt)
      #pragma unroll
      for (int r = 0; r < 4; ++r) {
        const float a = __shfl(sv[mt * 4 + r], src, 64);
        const float v = (mt == 0) ? vv0[r] : (mt == 1) ? vv1[r] : vv2[r];
        o += a * v;
      }
    op[nt] = o;
  }
  #pragma unroll
  for (int nt = 0; nt < 4; ++nt) {
    op[nt] += __shfl_xor(op[nt], 16, 64);
    op[nt] += __shfl_xor(op[nt], 32, 64);
  }
  {
    float oo = (lg == 0) ? op[0] : (lg == 1) ? op[1] : (lg == 2) ? op[2] : op[3];
    oo += ipb[2 * CC + lg * 16 + col];
    out[(size_t)m * CC + lg * 16 + col] = oo;
  }
}

extern "C" void kernel_launch(void* const* d_in, const int* in_sizes, int n_in,
                              void* d_out, int out_size, void* d_ws, size_t ws_size,
                              hipStream_t stream) {
  const float* vfeat  = (const float*)d_in[0];
  const float* vcoord = (const float*)d_in[1];
  const float* qcoord = (const float*)d_in[2];
  const int*   kidx   = (const int*)d_in[3];
  const unsigned char* km8  = (const unsigned char*)d_in[4];
  const int*           km32 = (const int*)d_in[4];
  const float* qpw = (const float*)d_in[5];
  const float* qpb = (const float*)d_in[6];
  const float* kpw = (const float*)d_in[7];
  const float* kpb = (const float*)d_in[8];
  const float* ipw = (const float*)d_in[9];
  const float* ipb = (const float*)d_in[10];
  const float* opw = (const float*)d_in[11];
  const float* opb = (const float*)d_in[12];
  const float* l1w = (const float*)d_in[13];
  const float* l1b = (const float*)d_in[14];
  const float* l2w = (const float*)d_in[15];
  const float* l2b = (const float*)d_in[16];
  const float* ng  = (const float*)d_in[17];
  const float* nb  = (const float*)d_in[18];
  const float* nm  = (const float*)d_in[19];
  const float* nv  = (const float*)d_in[20];
  const float* ow  = (const float*)d_in[21];
  const float* ob  = (const float*)d_in[22];
  const float* b2g = (const float*)d_in[23];
  const float* b2b = (const float*)d_in[24];
  const float* b2m = (const float*)d_in[25];
  const float* b2v = (const float*)d_in[26];

  const int M  = in_sizes[2] / 3;
  const int NV = in_sizes[0] / 64;
  float* ws  = (float*)d_ws;
  float* out = (float*)d_out;
  unsigned short* wsu = (unsigned short*)ws;
  const int* flag = (const int*)ws + 26880;

  const size_t need = (size_t)114688 + (size_t)M * 512 + (size_t)NV * 128 + (size_t)NV * 16;
  const int hot = (ws_size >= need) ? 1 : 0;
  unsigned short* qw  = wsu + QW_OFF_U16;
  unsigned short* vfb = wsu + QW_OFF_U16 + (size_t)M * 256;
  float4* vc4 = (float4*)(wsu + QW_OFF_U16 + (size_t)M * 256 + (size_t)NV * 64);

  if (hot) {
    const int qblocks = (M + 63) / 64;
    setup_kernel<<<210 + CASTB + qblocks, 256, 0, stream>>>(
        ipw, opw, l1w, l2w, ow, ng, nb, nm, nv, b2g, b2b, b2m, b2v, km8,
        vfeat, vcoord, qcoord, qpw, qpb, ipb, ws, vfb, vc4, qw, M, NV);
    attn_hot<<<(M + 3) / 4, 256, 0, stream>>>(vfb, vc4, qcoord, kidx,
                                              km8, km32, flag, kpw, kpb, ipb,
                                              wsu + 8192, qw, out, M);
  } else {
    prep_kernel<<<210, 256, 0, stream>>>(ipw, opw, l1w, l2w, ow,
                                         ng, nb, nm, nv, b2g, b2b, b2m, b2v, km8, ws);
    attn_fallback<<<(M + 3) / 4, 256, 0, stream>>>(vfeat, vcoord, qcoord, kidx,
                                                   km8, km32, flag,
                                                   qpw, qpb, kpw, kpb, ipb,
                                                   wsu, wsu + 4096, wsu + 8192, out, M);
  }
  chain2_kernel<<<(M + 15) / 16, 256, 0, stream>>>(out, wsu, opb, l1b, l2b, ob,
                                                   ws + 26624, ws + 26752, M);
}

// Round 16
// 79.803 us; speedup vs baseline: 1.0489x; 1.0489x over previous
//
#include <hip/hip_runtime.h>
#include <math.h>

#define CC 64
#define KK 48
#define HH 4

typedef __attribute__((ext_vector_type(8))) short s16x8;
typedef __attribute__((ext_vector_type(4))) short s16x4;
typedef __attribute__((ext_vector_type(4))) float f32x4;

// ws u16 layout: [0,4096) wq_bf | [4096,8192) wk2T_bf | [8192,12288) wv_bf
//   [12288,16384) opw_bf | [16384,32768) l1_bf | [32768,49152) l2_bf | [49152,53248) ow_bf
// ws f32: [26624,26752) nrm s,t | [26752,26880) bn2 s,t | [26880] flag(int)
// qw: u16 off 57344 [M][4][64] | vfb: u16 after qw [NV][64] | vc4: float4[NV] after vfb
#define QW_OFF_U16 57344
#define CASTB 1024

#define WAVEFENCE() asm volatile("s_waitcnt lgkmcnt(0)" ::: "memory")

__device__ __forceinline__ unsigned short f2bf(float f) {
  return (unsigned short)((__float_as_uint(f) + 0x8000u) >> 16);  // round-half-up
}
__device__ __forceinline__ float bf2f(unsigned short h) {
  return __uint_as_float(((unsigned)h) << 16);
}
// pack two f32 -> 2x bf16 (RNE) in one VALU op
__device__ __forceinline__ unsigned cvtpk(float lo, float hi) {
  unsigned r;
  asm("v_cvt_pk_bf16_f32 %0, %1, %2" : "=v"(r) : "v"(lo), "v"(hi));
  return r;
}

// ---------------- fused setup: prep [0,210) | castv [210,210+CASTB) | qprep rest ----------------
__global__ __launch_bounds__(256) void setup_kernel(
    const float* __restrict__ ipw, const float* __restrict__ opw,
    const float* __restrict__ l1w, const float* __restrict__ l2w,
    const float* __restrict__ ow,
    const float* __restrict__ ng, const float* __restrict__ nb,
    const float* __restrict__ nm, const float* __restrict__ nv,
    const float* __restrict__ b2g, const float* __restrict__ b2b,
    const float* __restrict__ b2m, const float* __restrict__ b2v,
    const unsigned char* __restrict__ km,
    const float* __restrict__ vf, const float* __restrict__ vcoord,
    const float* __restrict__ qcoord, const float* __restrict__ qpw,
    const float* __restrict__ qpb, const float* __restrict__ ipb,
    float* __restrict__ ws,
    unsigned short* __restrict__ vfb, float4* __restrict__ vc4,
    unsigned short* __restrict__ qw_out, int M, int NV)
{
  unsigned short* wsu = (unsigned short*)ws;
  const int b = blockIdx.x;

  if (b < 210) {                       // ---- prep part ----
    if (b == 209) {                    // mask dtype detect
      int any = 0;
      for (int i = threadIdx.x; i < 4096; i += 256)
        if ((i & 3) && km[i]) any = 1;
      __shared__ int sb;
      if (threadIdx.x == 0) sb = 0;
      __syncthreads();
      if (any) atomicOr(&sb, 1);
      __syncthreads();
      if (threadIdx.x == 0) ((int*)ws)[26880] = sb;
      return;
    }
    int e = b * 256 + threadIdx.x;
    if (e < 4096)        wsu[e] = f2bf(ipw[e]);
    else if (e < 8192)  { int i = e - 4096; int h = i >> 10, c = (i >> 4) & 63, d = i & 15;
                          wsu[e] = f2bf(ipw[(size_t)(64 + h * 16 + d) * 64 + c]); }
    else if (e < 12288)  wsu[e] = f2bf(ipw[e]);
    else if (e < 16384)  wsu[e] = f2bf(opw[e - 12288]);
    else if (e < 32768)  wsu[e] = f2bf(l1w[e - 16384]);
    else if (e < 49152)  wsu[e] = f2bf(l2w[e - 32768]);
    else if (e < 53248)  wsu[e] = f2bf(ow[e - 49152]);
    else if (e < 53312) { int c = e - 53248; float s = ng[c] / sqrtf(nv[c] + 1e-5f);
                          ws[26624 + c] = s; ws[26624 + 64 + c] = nb[c] - nm[c] * s; }
    else if (e < 53376) { int c = e - 53312; float s = b2g[c] / sqrtf(b2v[c] + 1e-5f);
                          ws[26752 + c] = s; ws[26752 + 64 + c] = b2b[c] - b2m[c] * s; }
    return;
  }

  if (b < 210 + CASTB) {               // ---- castv part (grid-stride) ----
    const int i0 = (b - 210) * 256 + threadIdx.x;
    const int stride = CASTB * 256;
    for (int i = i0; i < NV * 16; i += stride) {
      const float4 v = *(const float4*)(vf + (size_t)i * 4);
      s16x4 p; p[0] = (short)f2bf(v.x); p[1] = (short)f2bf(v.y);
      p[2] = (short)f2bf(v.z); p[3] = (short)f2bf(v.w);
      *(s16x4*)(vfb + (size_t)i * 4) = p;
    }
    for (int i = i0; i < NV; i += stride)
      vc4[i] = make_float4(vcoord[i * 3], vcoord[i * 3 + 1], vcoord[i * 3 + 2], 0.f);
    return;
  }

  // ---- qprep part: stage wq/wk to LDS coalesced, then MFMA ----
  {
    __shared__ __align__(16) unsigned short wql[4096];   // wq row-major, swz
    __shared__ __align__(16) unsigned short wkTl[4096];  // wk transposed [c][r], swz
    __shared__ __align__(16) unsigned short xa[4][1024];
    __shared__ float qc[4][48];
    const int w = threadIdx.x >> 6, l = threadIdx.x & 63;
    const int col = l & 15, lg = l >> 4;
    const int r0 = (b - 210 - CASTB) * 64 + w * 16;

    for (int i = threadIdx.x; i < 4096; i += 256) {
      const int r = i >> 6, d = i & 63;
      wql[i ^ ((r & 7) << 3)] = f2bf(ipw[i]);                       // wq[r][d]
      wkTl[(d * 64 + r) ^ ((d & 7) << 3)] = f2bf(ipw[4096 + i]);    // wk[r][d] -> [d][r]
    }
    if (l < 48) {
      int gi = r0 * 3 + l;
      qc[w][l] = (gi < M * 3) ? qcoord[gi] : 0.f;
    }
    const int c0 = col * 4;
    const float4 wA = *(const float4*)(qpw + c0 * 3);
    const float4 wB = *(const float4*)(qpw + c0 * 3 + 4);
    const float4 wC = *(const float4*)(qpw + c0 * 3 + 8);
    const float4 bq4 = *(const float4*)(qpb + c0);
    __syncthreads();

    #pragma unroll
    for (int i = 0; i < 4; ++i) {
      const int row = i * 4 + lg;
      const float x = qc[w][row * 3 + 0], y = qc[w][row * 3 + 1], z = qc[w][row * 3 + 2];
      s16x4 p;
      p[0] = (short)f2bf(fmaxf(wA.x * x + wA.y * y + wA.z * z + bq4.x, 0.f));
      p[1] = (short)f2bf(fmaxf(wA.w * x + wB.x * y + wB.y * z + bq4.y, 0.f));
      p[2] = (short)f2bf(fmaxf(wB.z * x + wB.w * y + wC.x * z + bq4.z, 0.f));
      p[3] = (short)f2bf(fmaxf(wC.y * x + wC.z * y + wC.w * z + bq4.w, 0.f));
      *(s16x4*)&xa[w][(row * 64 + c0) ^ ((row & 7) << 3)] = p;
    }
    __syncthreads();

    {
      s16x8 af0 = *(const s16x8*)&xa[w][(col * 64 + 0 + lg * 8) ^ ((col & 7) << 3)];
      s16x8 af1 = *(const s16x8*)&xa[w][(col * 64 + 32 + lg * 8) ^ ((col & 7) << 3)];
      f32x4 qv[4];
      #pragma unroll
      for (int nt = 0; nt < 4; ++nt) {
        const int n = nt * 16 + col;
        f32x4 acc = {0.f, 0.f, 0.f, 0.f};
        acc = __builtin_amdgcn_mfma_f32_16x16x32_bf16(af0,
                *(const s16x8*)&wql[(n * 64 + 0 + lg * 8) ^ ((col & 7) << 3)], acc, 0, 0, 0);
        acc = __builtin_amdgcn_mfma_f32_16x16x32_bf16(af1,
                *(const s16x8*)&wql[(n * 64 + 32 + lg * 8) ^ ((col & 7) << 3)], acc, 0, 0, 0);
        qv[nt] = acc;
      }
      __syncthreads();
      #pragma unroll
      for (int nt = 0; nt < 4; ++nt) {
        const int n = nt * 16 + col;
        const float bb = ipb[n];
        #pragma unroll
        for (int r = 0; r < 4; ++r) {
          const int row = lg * 4 + r;
          xa[w][(row * 64 + n) ^ ((row & 7) << 3)] = f2bf((qv[nt][r] + bb) * 0.25f);
        }
      }
    }
    __syncthreads();

    #pragma unroll
    for (int h = 0; h < HH; ++h) {
      s16x8 a = {0, 0, 0, 0, 0, 0, 0, 0};
      if (lg < 2)
        a = *(const s16x8*)&xa[w][(col * 64 + h * 16 + lg * 8) ^ ((col & 7) << 3)];
      #pragma unroll
      for (int nt = 0; nt < 4; ++nt) {
        const int n = nt * 16 + col;
        s16x8 bf = {0, 0, 0, 0, 0, 0, 0, 0};
        if (lg < 2)
          bf = *(const s16x8*)&wkTl[(n * 64 + h * 16 + lg * 8) ^ ((col & 7) << 3)];
        f32x4 acc = {0.f, 0.f, 0.f, 0.f};
        acc = __builtin_amdgcn_mfma_f32_16x16x32_bf16(a, bf, acc, 0, 0, 0);
        #pragma unroll
        for (int r = 0; r < 4; ++r) {
          const int m = lg * 4 + r;
          if (r0 + m < M)
            qw_out[(size_t)(r0 + m) * 256 + h * 64 + n] = f2bf(acc[r]);
        }
      }
    }
  }
}

// ---------------- attn_hot: r14 structure + cvt_pk bf16 pack in P5 (r15-proven) ----------------
__global__ __launch_bounds__(256, 4) void attn_hot(
    const unsigned short* __restrict__ vfb, const float4* __restrict__ vc4,
    const float* __restrict__ qcoord, const int* __restrict__ kidx,
    const unsigned char* __restrict__ km8, const int* __restrict__ km32,
    const int* __restrict__ maskfmt,
    const float* __restrict__ kpw, const float* __restrict__ kpb,
    const float* __restrict__ ipb,
    const unsigned short* __restrict__ wv_bf,
    const unsigned short* __restrict__ qw_pre,
    float* __restrict__ out, int M)
{
  __shared__ __align__(16) unsigned short shq[4][3456];
  __shared__ __align__(16) unsigned short wvl[4096];
  const int w = threadIdx.x >> 6, l = threadIdx.x & 63;
  const int col = l & 15, lg = l >> 4;
  int m = blockIdx.x * 4 + w;
  if (m >= M) m = M - 1;
  unsigned short* sh = shq[w];
  float* relf = (float*)(sh + 3072);
  const int is_u8 = *maskfmt;

  #pragma unroll
  for (int i = 0; i < 2; ++i) {
    const int ch = threadIdx.x * 2 + i;
    const int n = ch >> 3, g = ch & 7;
    const s16x8 v = *(const s16x8*)(wv_bf + n * 64 + g * 8);
    *(s16x8*)&wvl[n * 64 + ((g ^ (n & 7)) << 3)] = v;
  }

  const float qx = qcoord[m * 3 + 0], qy = qcoord[m * 3 + 1], qz = qcoord[m * 3 + 2];
  const int c0 = col * 4;
  const float4 kwA = *(const float4*)(kpw + c0 * 3);
  const float4 kwB = *(const float4*)(kpw + c0 * 3 + 4);
  const float4 kwC = *(const float4*)(kpw + c0 * 3 + 8);
  const float4 kbv = *(const float4*)(kpb + c0);

  // qw B-frags issued early: latency hides under P1/P5
  const s16x8 qb0 = *(const s16x8*)(qw_pre + (size_t)m * 256 + (col & 3) * 64 + 0 + lg * 8);
  const s16x8 qb1 = *(const s16x8*)(qw_pre + (size_t)m * 256 + (col & 3) * 64 + 32 + lg * 8);

  unsigned char msk = 0;
  if (l < KK) {
    const int idx = kidx[m * KK + l];
    msk = is_u8 ? km8[m * KK + l] : (unsigned char)(km32[m * KK + l] != 0);
    const float4 vc = vc4[idx];
    float4 rr;
    rr.x = vc.x - qx; rr.y = vc.y - qy; rr.z = vc.z - qz;
    rr.w = __int_as_float(idx);
    *(float4*)(relf + l * 4) = rr;
  }
  const unsigned long long bm = __ballot(l < KK && msk);
  __syncthreads();                       // covers wvl (cross-wave) + relf

  #pragma unroll
  for (int half = 0; half < 2; ++half) {
    float4 ra[6]; s16x4 va[6];
    #pragma unroll
    for (int j = 0; j < 6; ++j) {
      const int k = half * 24 + j * 4 + lg;
      ra[j] = *(const float4*)(relf + k * 4);
      va[j] = *(const s16x4*)(vfb + (size_t)__float_as_int(ra[j].w) * 64 + c0);
    }
    #pragma unroll
    for (int j = 0; j < 6; ++j) {
      const int k = half * 24 + j * 4 + lg;
      const float v0 = bf2f((unsigned short)va[j][0])
                     + fmaxf(kwA.x * ra[j].x + kwA.y * ra[j].y + kwA.z * ra[j].z + kbv.x, 0.f);
      const float v1 = bf2f((unsigned short)va[j][1])
                     + fmaxf(kwA.w * ra[j].x + kwB.x * ra[j].y + kwB.y * ra[j].z + kbv.y, 0.f);
      const float v2 = bf2f((unsigned short)va[j][2])
                     + fmaxf(kwB.z * ra[j].x + kwB.w * ra[j].y + kwC.x * ra[j].z + kbv.z, 0.f);
      const float v3 = bf2f((unsigned short)va[j][3])
                     + fmaxf(kwC.y * ra[j].x + kwC.z * ra[j].y + kwC.w * ra[j].z + kbv.w, 0.f);
      uint2 pp;
      pp.x = cvtpk(v0, v1);              // 1 VALU op replaces 2x f2bf + pack
      pp.y = cvtpk(v2, v3);
      *(uint2*)&sh[(k * 64 + c0) ^ ((k & 7) << 3)] = pp;
    }
  }
  WAVEFENCE();

  // ---- scores via MFMA ----
  s16x8 af[3][2];
  #pragma unroll
  for (int mt = 0; mt < 3; ++mt)
    #pragma unroll
    for (int kst = 0; kst < 2; ++kst) {
      const int row = mt * 16 + col;
      af[mt][kst] = *(const s16x8*)&sh[(row * 64 + kst * 32 + lg * 8) ^ ((row & 7) << 3)];
    }
  f32x4 sc[3];
  sc[0] = sc[1] = sc[2] = (f32x4){0.f, 0.f, 0.f, 0.f};
  __builtin_amdgcn_s_setprio(1);
  #pragma unroll
  for (int mt = 0; mt < 3; ++mt) {
    sc[mt] = __builtin_amdgcn_mfma_f32_16x16x32_bf16(af[mt][0], qb0, sc[mt], 0, 0, 0);
    sc[mt] = __builtin_amdgcn_mfma_f32_16x16x32_bf16(af[mt][1], qb1, sc[mt], 0, 0, 0);
  }
  __builtin_amdgcn_s_setprio(0);

  // ---- softmax ----
  float sv[12];
  {
    float mx = -INFINITY;
    #pragma unroll
    for (int mt = 0; mt < 3; ++mt)
      #pragma unroll
      for (int r = 0; r < 4; ++r) {
        const int key = mt * 16 + lg * 4 + r;
        float v = sc[mt][r];
        if ((bm >> key) & 1ull) v = -1e30f;
        sv[mt * 4 + r] = v;
        mx = fmaxf(mx, v);
      }
    mx = fmaxf(mx, __shfl_xor(mx, 16, 64));
    mx = fmaxf(mx, __shfl_xor(mx, 32, 64));
    float sum = 0.f;
    #pragma unroll
    for (int i = 0; i < 12; ++i) { float e = __expf(sv[i] - mx); sv[i] = e; sum += e; }
    sum += __shfl_xor(sum, 16, 64);
    sum += __shfl_xor(sum, 32, 64);
    const float inv = 1.f / sum;
    #pragma unroll
    for (int i = 0; i < 12; ++i) sv[i] *= inv;
  }
  if (col < HH) {
    #pragma unroll
    for (int mt = 0; mt < 3; ++mt)
      #pragma unroll
      for (int r = 0; r < 4; ++r)
        relf[(mt * 16 + lg * 4 + r) * 4 + col] = sv[mt * 4 + r];
  }
  WAVEFENCE();

  // ---- vv = kin @ wv^T, then o[c] = sum_k a[k][h(c)]*vv[k][c] + bv ----
  f32x4 vva[4][3];
  __builtin_amdgcn_s_setprio(1);
  #pragma unroll
  for (int nt = 0; nt < 4; ++nt) {
    const int n = nt * 16 + col;
    vva[nt][0] = vva[nt][1] = vva[nt][2] = (f32x4){0.f, 0.f, 0.f, 0.f};
    #pragma unroll
    for (int kst = 0; kst < 2; ++kst) {
      const s16x8 bb = *(const s16x8*)&wvl[(n * 64 + kst * 32 + lg * 8) ^ ((n & 7) << 3)];
      vva[nt][0] = __builtin_amdgcn_mfma_f32_16x16x32_bf16(af[0][kst], bb, vva[nt][0], 0, 0, 0);
      vva[nt][1] = __builtin_amdgcn_mfma_f32_16x16x32_bf16(af[1][kst], bb, vva[nt][1], 0, 0, 0);
      vva[nt][2] = __builtin_amdgcn_mfma_f32_16x16x32_bf16(af[2][kst], bb, vva[nt][2], 0, 0, 0);
    }
  }
  __builtin_amdgcn_s_setprio(0);
  float op[4] = {0.f, 0.f, 0.f, 0.f};
  #pragma unroll
  for (int mt = 0; mt < 3; ++mt)
    #pragma unroll
    for (int r = 0; r < 4; ++r) {
      const float4 a4 = *(const float4*)(relf + (mt * 16 + lg * 4 + r) * 4);
      op[0] += a4.x * vva[0][mt][r];
      op[1] += a4.y * vva[1][mt][r];
      op[2] += a4.z * vva[2][mt][r];
      op[3] += a4.w * vva[3][mt][r];
    }
  #pragma unroll
  for (int nt = 0; nt < 4; ++nt) {
    op[nt] += __shfl_xor(op[nt], 16, 64);
    op[nt] += __shfl_xor(op[nt], 32, 64);
  }
  {
    float oo = (lg == 0) ? op[0] : (lg == 1) ? op[1] : (lg == 2) ? op[2] : op[3];
    oo += ipb[2 * CC + lg * 16 + col];
    out[(size_t)m * CC + lg * 16 + col] = oo;
  }
}

// ---------------- chain2: 16 rows/block, 4 cooperative waves ----------------
__global__ __launch_bounds__(256, 4) void chain2_kernel(
    float* __restrict__ inout, const unsigned short* __restrict__ wsu,
    const float* __restrict__ opb, const float* __restrict__ l1b,
    const float* __restrict__ l2b, const float* __restrict__ ob,
    const float* __restrict__ nrm, const float* __restrict__ bn2, int M)
{
  __shared__ __align__(16) unsigned short XA[1024];
  __shared__ __align__(16) unsigned short XH[4096];
  __shared__ __align__(16) unsigned short XB[1024];
  const int w = threadIdx.x >> 6, l = threadIdx.x & 63;
  const int col = l & 15, lg = l >> 4;
  const int r0 = blockIdx.x * 16;

  const unsigned short* opw_bf = wsu + 12288;
  const unsigned short* l1_bf  = wsu + 16384;
  const unsigned short* l2_bf  = wsu + 32768;
  const unsigned short* ow_bf  = wsu + 49152;

  {
    const int i = threadIdx.x;
    const int row = i >> 4, cb = (i & 15) * 4;
    float4 v = make_float4(0.f, 0.f, 0.f, 0.f);
    if (r0 + row < M) v = *(const float4*)(&inout[(size_t)(r0 + row) * 64 + cb]);
    s16x4 p; p[0] = (short)f2bf(v.x); p[1] = (short)f2bf(v.y);
    p[2] = (short)f2bf(v.z); p[3] = (short)f2bf(v.w);
    *(s16x4*)&XA[(row * 64 + cb) ^ ((row & 7) << 3)] = p;
  }
  __syncthreads();

  s16x8 afa[2];
  #pragma unroll
  for (int kst = 0; kst < 2; ++kst)
    afa[kst] = *(const s16x8*)&XA[(col * 64 + kst * 32 + lg * 8) ^ ((col & 7) << 3)];
  f32x4 att;
  {
    f32x4 acc = {0.f, 0.f, 0.f, 0.f};
    #pragma unroll
    for (int kst = 0; kst < 2; ++kst) {
      const s16x8 bb = *(const s16x8*)&opw_bf[(w * 16 + col) * 64 + kst * 32 + lg * 8];
      acc = __builtin_amdgcn_mfma_f32_16x16x32_bf16(afa[kst], bb, acc, 0, 0, 0);
    }
    const float bias = opb[w * 16 + col];
    #pragma unroll
    for (int r = 0; r < 4; ++r) {
      acc[r] += bias;
      const int row = lg * 4 + r;
      XB[(row * 64 + w * 16 + col) ^ ((row & 7) << 3)] = (short)f2bf(acc[r]);
    }
    att = acc;
  }
  __syncthreads();

  {
    s16x8 afb[2];
    #pragma unroll
    for (int kst = 0; kst < 2; ++kst)
      afb[kst] = *(const s16x8*)&XB[(col * 64 + kst * 32 + lg * 8) ^ ((col & 7) << 3)];
    #pragma unroll
    for (int nt2 = 0; nt2 < 4; ++nt2) {
      const int ntg = w * 4 + nt2;
      f32x4 acc = {0.f, 0.f, 0.f, 0.f};
      #pragma unroll
      for (int kst = 0; kst < 2; ++kst) {
        const s16x8 bb = *(const s16x8*)&l1_bf[(ntg * 16 + col) * 64 + kst * 32 + lg * 8];
        acc = __builtin_amdgcn_mfma_f32_16x16x32_bf16(afb[kst], bb, acc, 0, 0, 0);
      }
      const float bias = l1b[ntg * 16 + col];
      #pragma unroll
      for (int r = 0; r < 4; ++r) {
        const float h = fmaxf(acc[r] + bias, 0.f);
        const int row = lg * 4 + r;
        XH[(row * 256 + ntg * 16 + col) ^ ((row & 7) << 3)] = (short)f2bf(h);
      }
    }
  }
  __syncthreads();

  {
    s16x8 afh[8];
    #pragma unroll
    for (int kst = 0; kst < 8; ++kst)
      afh[kst] = *(const s16x8*)&XH[(col * 256 + kst * 32 + lg * 8) ^ ((col & 7) << 3)];
    f32x4 acc = {0.f, 0.f, 0.f, 0.f};
    #pragma unroll
    for (int kst = 0; kst < 8; ++kst) {
      const s16x8 bb = *(const s16x8*)&l2_bf[(w * 16 + col) * 256 + kst * 32 + lg * 8];
      acc = __builtin_amdgcn_mfma_f32_16x16x32_bf16(afh[kst], bb, acc, 0, 0, 0);
    }
    const int nc = w * 16 + col;
    const float bias = l2b[nc], sN = nrm[nc], tN = nrm[64 + nc];
    __syncthreads();                     // G2's XB reads done before overwrite
    #pragma unroll
    for (int r = 0; r < 4; ++r) {
      const float x = (att[r] + acc[r] + bias) * sN + tN;
      const int row = lg * 4 + r;
      XB[(row * 64 + nc) ^ ((row & 7) << 3)] = (short)f2bf(x);
    }
  }
  __syncthreads();

  {
    s16x8 afx[2];
    #pragma unroll
    for (int kst = 0; kst < 2; ++kst)
      afx[kst] = *(const s16x8*)&XB[(col * 64 + kst * 32 + lg * 8) ^ ((col & 7) << 3)];
    f32x4 acc = {0.f, 0.f, 0.f, 0.f};
    #pragma unroll
    for (int kst = 0; kst < 2; ++kst) {
      const s16x8 bb = *(const s16x8*)&ow_bf[(w * 16 + col) * 64 + kst * 32 + lg * 8];
      acc = __builtin_amdgcn_mfma_f32_16x16x32_bf16(afx[kst], bb, acc, 0, 0, 0);
    }
    const int nc = w * 16 + col;
    const float bias = ob[nc], sB = bn2[nc], tB = bn2[64 + nc];
    #pragma unroll
    for (int r = 0; r < 4; ++r) {
      const float y = fmaxf((acc[r] + bias) * sB + tB, 0.f);
      const int q = r0 + lg * 4 + r;
      if (q < M) inout[(size_t)q * 64 + nc] = y;
    }
  }
}

// ---------------- fallback kernels (ws too small): r11-proven ----------------
__global__ __launch_bounds__(256) void prep_kernel(
    const float* __restrict__ ipw, const float* __restrict__ opw,
    const float* __restrict__ l1w, const float* __restrict__ l2w,
    const float* __restrict__ ow,
    const float* __restrict__ ng, const float* __restrict__ nb,
    const float* __restrict__ nm, const float* __restrict__ nv,
    const float* __restrict__ b2g, const float* __restrict__ b2b,
    const float* __restrict__ b2m, const float* __restrict__ b2v,
    const unsigned char* __restrict__ km,
    float* __restrict__ ws)
{
  unsigned short* wsu = (unsigned short*)ws;
  if (blockIdx.x == 209) {
    int any = 0;
    for (int i = threadIdx.x; i < 4096; i += 256)
      if ((i & 3) && km[i]) any = 1;
    __shared__ int sb;
    if (threadIdx.x == 0) sb = 0;
    __syncthreads();
    if (any) atomicOr(&sb, 1);
    __syncthreads();
    if (threadIdx.x == 0) ((int*)ws)[26880] = sb;
    return;
  }
  int e = blockIdx.x * 256 + threadIdx.x;
  if (e < 4096)        wsu[e] = f2bf(ipw[e]);
  else if (e < 8192)  { int i = e - 4096; int h = i >> 10, c = (i >> 4) & 63, d = i & 15;
                        wsu[e] = f2bf(ipw[(size_t)(64 + h * 16 + d) * 64 + c]); }
  else if (e < 12288)  wsu[e] = f2bf(ipw[e]);
  else if (e < 16384)  wsu[e] = f2bf(opw[e - 12288]);
  else if (e < 32768)  wsu[e] = f2bf(l1w[e - 16384]);
  else if (e < 49152)  wsu[e] = f2bf(l2w[e - 32768]);
  else if (e < 53248)  wsu[e] = f2bf(ow[e - 49152]);
  else if (e < 53312) { int c = e - 53248; float s = ng[c] / sqrtf(nv[c] + 1e-5f);
                        ws[26624 + c] = s; ws[26624 + 64 + c] = nb[c] - nm[c] * s; }
  else if (e < 53376) { int c = e - 53312; float s = b2g[c] / sqrtf(b2v[c] + 1e-5f);
                        ws[26752 + c] = s; ws[26752 + 64 + c] = b2b[c] - b2m[c] * s; }
}

__global__ __launch_bounds__(256, 4) void attn_fallback(
    const float* __restrict__ vfeat, const float* __restrict__ vcoord,
    const float* __restrict__ qcoord, const int* __restrict__ kidx,
    const unsigned char* __restrict__ km8, const int* __restrict__ km32,
    const int* __restrict__ maskfmt,
    const float* __restrict__ qpw, const float* __restrict__ qpb,
    const float* __restrict__ kpw, const float* __restrict__ kpb,
    const float* __restrict__ ipb,
    const unsigned short* __restrict__ wq_bf,
    const unsigned short* __restrict__ wk2T_bf,
    const unsigned short* __restrict__ wv_bf,
    float* __restrict__ out, int M)
{
  __shared__ __align__(16) unsigned short shq[4][3776];
  __shared__ __align__(16) unsigned short wvl[4096];
  const int w = threadIdx.x >> 6, l = threadIdx.x & 63;
  const int col = l & 15, lg = l >> 4;
  int m = blockIdx.x * 4 + w;
  if (m >= M) m = M - 1;
  unsigned short* sh = shq[w];
  const int is_u8 = *maskfmt;
  float* relf = (float*)sh + 1696;

  #pragma unroll
  for (int i = 0; i < 2; ++i) {
    const int ch = threadIdx.x * 2 + i;
    const int n = ch >> 3, g = ch & 7;
    const s16x8 v = *(const s16x8*)(wv_bf + n * 64 + g * 8);
    *(s16x8*)&wvl[n * 64 + ((g ^ (n & 7)) << 3)] = v;
  }

  const float qx = qcoord[m * 3 + 0], qy = qcoord[m * 3 + 1], qz = qcoord[m * 3 + 2];
  const int c0 = col * 4;
  const float4 kwA = *(const float4*)(kpw + c0 * 3);
  const float4 kwB = *(const float4*)(kpw + c0 * 3 + 4);
  const float4 kwC = *(const float4*)(kpw + c0 * 3 + 8);
  const float4 kbv = *(const float4*)(kpb + c0);

  {
    float v = qpw[l * 3 + 0] * qx + qpw[l * 3 + 1] * qy + qpw[l * 3 + 2] * qz + qpb[l];
    sh[3328 + l] = f2bf(fmaxf(v, 0.f));
  }
  unsigned char msk = 0;
  if (l < KK) {
    int idx = kidx[m * KK + l];
    msk = is_u8 ? km8[m * KK + l] : (unsigned char)(km32[m * KK + l] != 0);
    relf[l * 4 + 0] = vcoord[idx * 3 + 0] - qx;
    relf[l * 4 + 1] = vcoord[idx * 3 + 1] - qy;
    relf[l * 4 + 2] = vcoord[idx * 3 + 2] - qz;
    relf[l * 4 + 3] = __int_as_float(idx);
  }
  const unsigned long long bm = __ballot(l < KK && msk);
  __syncthreads();

  {
    f32x4 qacc[4];
    #pragma unroll
    for (int nt = 0; nt < 4; ++nt) qacc[nt] = (f32x4){0.f, 0.f, 0.f, 0.f};
    #pragma unroll
    for (int kst = 0; kst < 2; ++kst) {
      const s16x8 a = *(const s16x8*)&sh[3328 + kst * 32 + lg * 8];
      #pragma unroll
      for (int nt = 0; nt < 4; ++nt) {
        const s16x8 b = *(const s16x8*)(wq_bf + (nt * 16 + col) * 64 + kst * 32 + lg * 8);
        qacc[nt] = __builtin_amdgcn_mfma_f32_16x16x32_bf16(a, b, qacc[nt], 0, 0, 0);
      }
    }
    __syncthreads();
    if (lg == 0) {
      #pragma unroll
      for (int nt = 0; nt < 4; ++nt)
        sh[3328 + nt * 16 + col] = f2bf((qacc[nt][0] + ipb[nt * 16 + col]) * 0.25f);
    }
    __syncthreads();
    f32x4 wacc[4];
    #pragma unroll
    for (int nt = 0; nt < 4; ++nt) wacc[nt] = (f32x4){0.f, 0.f, 0.f, 0.f};
    #pragma unroll
    for (int kst = 0; kst < 2; ++kst) {
      const int hblk = kst * 2 + (lg >> 1);
      s16x8 a = {0, 0, 0, 0, 0, 0, 0, 0};
      if (col == hblk) a = *(const s16x8*)&sh[3328 + kst * 32 + lg * 8];
      #pragma unroll
      for (int nt = 0; nt < 4; ++nt) {
        const s16x8 b = *(const s16x8*)(wk2T_bf + hblk * 1024 + (nt * 16 + col) * 16 + (lg & 1) * 8);
        wacc[nt] = __builtin_amdgcn_mfma_f32_16x16x32_bf16(a, b, wacc[nt], 0, 0, 0);
      }
    }
    if (lg == 0) {
      #pragma unroll
      for (int nt = 0; nt < 4; ++nt)
        #pragma unroll
        for (int r = 0; r < 4; ++r)
          sh[3072 + r * 64 + nt * 16 + col] = f2bf(wacc[nt][r]);
    }
  }

  #pragma unroll
  for (int half = 0; half < 2; ++half) {
    float4 ra[6], va[6];
    #pragma unroll
    for (int j = 0; j < 6; ++j) {
      const int k = half * 24 + j * 4 + lg;
      ra[j] = *(const float4*)(relf + k * 4);
      va[j] = *(const float4*)(vfeat + (size_t)__float_as_int(ra[j].w) * 64 + c0);
    }
    #pragma unroll
    for (int j = 0; j < 6; ++j) {
      const int k = half * 24 + j * 4 + lg;
      const float p0 = fmaxf(kwA.x * ra[j].x + kwA.y * ra[j].y + kwA.z * ra[j].z + kbv.x, 0.f);
      const float p1 = fmaxf(kwA.w * ra[j].x + kwB.x * ra[j].y + kwB.y * ra[j].z + kbv.y, 0.f);
      const float p2 = fmaxf(kwB.z * ra[j].x + kwB.w * ra[j].y + kwC.x * ra[j].z + kbv.z, 0.f);
      const float p3 = fmaxf(kwC.y * ra[j].x + kwC.z * ra[j].y + kwC.w * ra[j].z + kbv.w, 0.f);
      s16x4 p;
      p[0] = (short)f2bf(va[j].x + p0); p[1] = (short)f2bf(va[j].y + p1);
      p[2] = (short)f2bf(va[j].z + p2); p[3] = (short)f2bf(va[j].w + p3);
      *(s16x4*)&sh[(k * 64 + c0) ^ ((k & 7) << 3)] = p;
    }
  }
  __syncthreads();

  s16x8 af[3][2];
  #pragma unroll
  for (int mt = 0; mt < 3; ++mt)
    #pragma unroll
    for (int kst = 0; kst < 2; ++kst) {
      const int row = mt * 16 + col;
      af[mt][kst] = *(const s16x8*)&sh[(row * 64 + kst * 32 + lg * 8) ^ ((row & 7) << 3)];
    }
  f32x4 sc[3];
  sc[0] = sc[1] = sc[2] = (f32x4){0.f, 0.f, 0.f, 0.f};
  #pragma unroll
  for (int kst = 0; kst < 2; ++kst) {
    const s16x8 b = *(const s16x8*)&sh[3072 + (col & 3) * 64 + kst * 32 + lg * 8];
    #pragma unroll
    for (int mt = 0; mt < 3; ++mt)
      sc[mt] = __builtin_amdgcn_mfma_f32_16x16x32_bf16(af[mt][kst], b, sc[mt], 0, 0, 0);
  }

  float sv[12];
  {
    float mx = -INFINITY;
    #pragma unroll
    for (int mt = 0; mt < 3; ++mt)
      #pragma unroll
      for (int r = 0; r < 4; ++r) {
        const int key = mt * 16 + lg * 4 + r;
        float v = sc[mt][r];
        if ((bm >> key) & 1ull) v = -1e30f;
        sv[mt * 4 + r] = v;
        mx = fmaxf(mx, v);
      }
    mx = fmaxf(mx, __shfl_xor(mx, 16, 64));
    mx = fmaxf(mx, __shfl_xor(mx, 32, 64));
    float sum = 0.f;
    #pragma unroll
    for (int i = 0; i < 12; ++i) { float e = __expf(sv[i] - mx); sv[i] = e; sum += e; }
    sum += __shfl_xor(sum, 16, 64);
    sum += __shfl_xor(sum, 32, 64);
    const float inv = 1.f / sum;
    #pragma unroll
    for (int i = 0; i < 12; ++i) sv[i] *= inv;
  }

  float op[4];
  #pragma unroll
  for (int nt = 0; nt < 4; ++nt) {
    const int n = nt * 16 + col;
    f32x4 vv0 = {0.f, 0.f, 0.f, 0.f}, vv1 = vv0, vv2 = vv0;
    #pragma unroll
    for (int kst = 0; kst < 2; ++kst) {
      const s16x8 b = *(const s16x8*)&wvl[(n * 64 + kst * 32 + lg * 8) ^ ((n & 7) << 3)];
      vv0 = __builtin_amdgcn_mfma_f32_16x16x32_bf16(af[0][kst], b, vv0, 0, 0, 0);
      vv1 = __builtin_amdgcn_mfma_f32_16x16x32_bf16(af[1][kst], b, vv1, 0, 0, 0);
      vv2 = __builtin_amdgcn_mfma_f32_16x16x32_bf16(af[2][kst], b, vv2, 0, 0, 0);
    }
    const int src = lg * 16 + nt;
    float o = 0.f;
    #pragma unroll
    for (int mt = 0; mt < 3; ++mt)
      #pragma unroll
      for (int r = 0; r < 4; ++r) {
        const float a = __shfl(sv[mt * 4 + r], src, 64);
        const float v = (mt == 0) ? vv0[r] : (mt == 1) ? vv1[r] : vv2[r];
        o += a * v;
      }
    op[nt] = o;
  }
  #pragma unroll
  for (int nt = 0; nt < 4; ++nt) {
    op[nt] += __shfl_xor(op[nt], 16, 64);
    op[nt] += __shfl_xor(op[nt], 32, 64);
  }
  {
    float oo = (lg == 0) ? op[0] : (lg == 1) ? op[1] : (lg == 2) ? op[2] : op[3];
    oo += ipb[2 * CC + lg * 16 + col];
    out[(size_t)m * CC + lg * 16 + col] = oo;
  }
}

extern "C" void kernel_launch(void* const* d_in, const int* in_sizes, int n_in,
                              void* d_out, int out_size, void* d_ws, size_t ws_size,
                              hipStream_t stream) {
  const float* vfeat  = (const float*)d_in[0];
  const float* vcoord = (const float*)d_in[1];
  const float* qcoord = (const float*)d_in[2];
  const int*   kidx   = (const int*)d_in[3];
  const unsigned char* km8  = (const unsigned char*)d_in[4];
  const int*           km32 = (const int*)d_in[4];
  const float* qpw = (const float*)d_in[5];
  const float* qpb = (const float*)d_in[6];
  const float* kpw = (const float*)d_in[7];
  const float* kpb = (const float*)d_in[8];
  const float* ipw = (const float*)d_in[9];
  const float* ipb = (const float*)d_in[10];
  const float* opw = (const float*)d_in[11];
  const float* opb = (const float*)d_in[12];
  const float* l1w = (const float*)d_in[13];
  const float* l1b = (const float*)d_in[14];
  const float* l2w = (const float*)d_in[15];
  const float* l2b = (const float*)d_in[16];
  const float* ng  = (const float*)d_in[17];
  const float* nb  = (const float*)d_in[18];
  const float* nm  = (const float*)d_in[19];
  const float* nv  = (const float*)d_in[20];
  const float* ow  = (const float*)d_in[21];
  const float* ob  = (const float*)d_in[22];
  const float* b2g = (const float*)d_in[23];
  const float* b2b = (const float*)d_in[24];
  const float* b2m = (const float*)d_in[25];
  const float* b2v = (const float*)d_in[26];

  const int M  = in_sizes[2] / 3;
  const int NV = in_sizes[0] / 64;
  float* ws  = (float*)d_ws;
  float* out = (float*)d_out;
  unsigned short* wsu = (unsigned short*)ws;
  const int* flag = (const int*)ws + 26880;

  const size_t need = (size_t)114688 + (size_t)M * 512 + (size_t)NV * 128 + (size_t)NV * 16;
  const int hot = (ws_size >= need) ? 1 : 0;
  unsigned short* qw  = wsu + QW_OFF_U16;
  unsigned short* vfb = wsu + QW_OFF_U16 + (size_t)M * 256;
  float4* vc4 = (float4*)(wsu + QW_OFF_U16 + (size_t)M * 256 + (size_t)NV * 64);

  if (hot) {
    const int qblocks = (M + 63) / 64;
    setup_kernel<<<210 + CASTB + qblocks, 256, 0, stream>>>(
        ipw, opw, l1w, l2w, ow, ng, nb, nm, nv, b2g, b2b, b2m, b2v, km8,
        vfeat, vcoord, qcoord, qpw, qpb, ipb, ws, vfb, vc4, qw, M, NV);
    attn_hot<<<(M + 3) / 4, 256, 0, stream>>>(vfb, vc4, qcoord, kidx,
                                              km8, km32, flag, kpw, kpb, ipb,
                                              wsu + 8192, qw, out, M);
  } else {
    prep_kernel<<<210, 256, 0, stream>>>(ipw, opw, l1w, l2w, ow,
                                         ng, nb, nm, nv, b2g, b2b, b2m, b2v, km8, ws);
    attn_fallback<<<(M + 3) / 4, 256, 0, stream>>>(vfeat, vcoord, qcoord, kidx,
                                                   km8, km32, flag,
                                                   qpw, qpb, kpw, kpb, ipb,
                                                   wsu, wsu + 4096, wsu + 8192, out, M);
  }
  chain2_kernel<<<(M + 15) / 16, 256, 0, stream>>>(out, wsu, opb, l1b, l2b, ob,
                                                   ws + 26624, ws + 26752, M);
}